// Round 1
// baseline (626.093 us; speedup 1.0000x reference)
//
#include <hip/hip_runtime.h>
#include <hip/hip_bf16.h>

#define VOCAB 32000
#define EMBED 128
#define CTX 8
#define BATCH 4096

typedef short bf16x8 __attribute__((ext_vector_type(8)));
typedef float f32x4 __attribute__((ext_vector_type(4)));

__device__ __forceinline__ unsigned short f2bf_rne(float f) {
    union { float f; unsigned int u; } v; v.f = f;
    unsigned int u = v.u;
    unsigned int r = (u + 0x7FFFu + ((u >> 16) & 1u)) >> 16;
    return (unsigned short)r;
}

// Kernel 1: CBOW gather-sum (padding_idx=0) + fp32->bf16 convert.
// One block per sample, 128 threads = one embedding column each.
__global__ void gather_sum_kernel(const int* __restrict__ x,
                                  const float* __restrict__ emb,
                                  unsigned short* __restrict__ A) {
    const int i = blockIdx.x;    // sample
    const int j = threadIdx.x;   // embed dim 0..127
    const int* xr = x + i * CTX;
    float s = 0.0f;
#pragma unroll
    for (int c = 0; c < CTX; ++c) {
        const int idx = xr[c];          // uniform across block -> uniform branch
        if (idx != 0) s += emb[(size_t)idx * EMBED + j];
    }
    A[i * EMBED + j] = f2bf_rne(s);
}

// Kernel 2: W fp32 -> bf16. 4 elements/thread, float4 in / ushort4 out.
__global__ void convert_w_kernel(const float* __restrict__ W,
                                 unsigned short* __restrict__ Wb) {
    const int t = blockIdx.x * 256 + threadIdx.x;   // 1,024,000 threads
    const float4 v = ((const float4*)W)[t];
    ushort4 o;
    o.x = f2bf_rne(v.x);
    o.y = f2bf_rne(v.y);
    o.z = f2bf_rne(v.z);
    o.w = f2bf_rne(v.w);
    ((ushort4*)Wb)[t] = o;
}

// Kernel 3: C[4096,32000] = A[4096,128] @ Wb[32000,128]^T + bias.
// Swapped operands: MFMA-M = vocab (n), MFMA-N = batch (m), so each lane's
// 4 accumulator regs are 4 CONSECUTIVE vocab columns -> float4 stores.
// K=128 = 4 MFMA k-steps, everything register-resident, no LDS (waves own
// disjoint N-strips; LDS would give zero sharing).
// Block = 256 thr = 4 waves. Block tile: 64 M x 256 N (wave w: N [64w,64w+64)).
__global__ __launch_bounds__(256) void cbow_gemm_kernel(
    const unsigned short* __restrict__ A,    // [BATCH][128] bf16 (summed)
    const unsigned short* __restrict__ Wb,   // [VOCAB][128] bf16
    const float* __restrict__ bias,          // [VOCAB]
    float* __restrict__ C)                   // [BATCH][VOCAB]
{
    const int tid  = threadIdx.x;
    const int wave = tid >> 6;
    const int lane = tid & 63;
    const int lr   = lane & 15;   // free-dim index inside a 16x16 tile
    const int quad = lane >> 4;   // k-chunk selector (k = quad*8 + j)
    const int nwave = blockIdx.x * 256 + wave * 64;  // vocab start, this wave
    const int mbase = blockIdx.y * 64;               // batch start, this block

    // B-operand frags: summed[m][k]; n_mfma = lr -> batch row, k = s*32+quad*8+j.
    // 16B aligned contiguous loads; A is 1 MB -> L2-hot across all N-blocks.
    bf16x8 bfrag[4][4];
#pragma unroll
    for (int mt = 0; mt < 4; ++mt) {
        const unsigned short* row = A + (size_t)(mbase + mt * 16 + lr) * EMBED;
#pragma unroll
        for (int s = 0; s < 4; ++s)
            bfrag[mt][s] = *(const bf16x8*)(row + s * 32 + quad * 8);
    }

    f32x4 acc[4][4];
#pragma unroll
    for (int nt = 0; nt < 4; ++nt)
#pragma unroll
        for (int mt = 0; mt < 4; ++mt)
            acc[nt][mt] = (f32x4){0.f, 0.f, 0.f, 0.f};

#pragma unroll
    for (int nt = 0; nt < 4; ++nt) {
        // A-operand frags: W[n][k]; m_mfma = lr -> vocab row.
        const unsigned short* wrow =
            Wb + (size_t)(nwave + nt * 16 + lr) * EMBED;
        bf16x8 wf[4];
#pragma unroll
        for (int s = 0; s < 4; ++s)
            wf[s] = *(const bf16x8*)(wrow + s * 32 + quad * 8);
#pragma unroll
        for (int s = 0; s < 4; ++s)
#pragma unroll
            for (int mt = 0; mt < 4; ++mt)
                acc[nt][mt] = __builtin_amdgcn_mfma_f32_16x16x32_bf16(
                    wf[s], bfrag[mt][s], acc[nt][mt], 0, 0, 0);
    }

    // Epilogue: C/D layout (swapped): vocab n = nt*16 + quad*4 + reg,
    // batch m = lr. One float4 store per tile, 16B aligned (VOCAB%4==0).
#pragma unroll
    for (int nt = 0; nt < 4; ++nt) {
        const int n0 = nwave + nt * 16 + quad * 4;
        const f32x4 bv = *(const f32x4*)(bias + n0);
#pragma unroll
        for (int mt = 0; mt < 4; ++mt) {
            const int m = mbase + mt * 16 + lr;
            const f32x4 v = acc[nt][mt] + bv;
            *(f32x4*)(C + (size_t)m * VOCAB + n0) = v;
        }
    }
}

extern "C" void kernel_launch(void* const* d_in, const int* in_sizes, int n_in,
                              void* d_out, int out_size, void* d_ws, size_t ws_size,
                              hipStream_t stream) {
    const int*   x    = (const int*)d_in[0];     // [4096,8]
    const float* emb  = (const float*)d_in[1];   // [32000,128]
    const float* W    = (const float*)d_in[2];   // [32000,128]
    const float* bias = (const float*)d_in[3];   // [32000]
    float* out = (float*)d_out;                  // [4096,32000]

    unsigned short* A  = (unsigned short*)d_ws;            // 1 MB: summed bf16
    unsigned short* Wb = A + (size_t)BATCH * EMBED;        // 8.2 MB: W bf16

    gather_sum_kernel<<<BATCH, EMBED, 0, stream>>>(x, emb, A);
    convert_w_kernel<<<(VOCAB * EMBED / 4) / 256, 256, 0, stream>>>(W, Wb);

    dim3 grid(VOCAB / 256, BATCH / 64);   // 125 x 64 = 8000 blocks
    cbow_gemm_kernel<<<grid, 256, 0, stream>>>(A, Wb, bias, out);
}

// Round 2
// 597.362 us; speedup vs baseline: 1.0481x; 1.0481x over previous
//
#include <hip/hip_runtime.h>
#include <hip/hip_bf16.h>

#define VOCAB 32000
#define EMBED 128
#define CTX 8
#define BATCH 4096

typedef short bf16x8 __attribute__((ext_vector_type(8)));
typedef float f32x4 __attribute__((ext_vector_type(4)));

__device__ __forceinline__ unsigned short f2bf_rne(float f) {
    union { float f; unsigned int u; } v; v.f = f;
    unsigned int u = v.u;
    unsigned int r = (u + 0x7FFFu + ((u >> 16) & 1u)) >> 16;
    return (unsigned short)r;
}

// Kernel 1: CBOW gather-sum (padding_idx=0) + fp32->bf16 convert.
__global__ void gather_sum_kernel(const int* __restrict__ x,
                                  const float* __restrict__ emb,
                                  unsigned short* __restrict__ A) {
    const int i = blockIdx.x;    // sample
    const int j = threadIdx.x;   // embed dim 0..127
    const int* xr = x + i * CTX;
    float s = 0.0f;
#pragma unroll
    for (int c = 0; c < CTX; ++c) {
        const int idx = xr[c];          // uniform across block
        if (idx != 0) s += emb[(size_t)idx * EMBED + j];
    }
    A[i * EMBED + j] = f2bf_rne(s);
}

// Kernel 2: W fp32 -> bf16.
__global__ void convert_w_kernel(const float* __restrict__ W,
                                 unsigned short* __restrict__ Wb) {
    const int t = blockIdx.x * 256 + threadIdx.x;
    const float4 v = ((const float4*)W)[t];
    ushort4 o;
    o.x = f2bf_rne(v.x);
    o.y = f2bf_rne(v.y);
    o.z = f2bf_rne(v.z);
    o.w = f2bf_rne(v.w);
    ((ushort4*)Wb)[t] = o;
}

// Kernel 3: C[4096,32000] = A[4096,128] @ Wb[32000,128]^T + bias.
// R1 restructure: W fragments are REGISTER-RESIDENT per block (loaded once),
// block loops over 8 m-tiles of 64 rows. Kills the 64x W re-fetch that was
// thrashing LLC against the 524 MB C-write stream. C stores are nontemporal
// (nobody re-reads C) to keep A/W hot in L2.
// Swapped operands: MFMA-M = vocab, MFMA-N = batch -> lane's 4 acc regs are
// 4 consecutive vocab cols -> float4 stores.
__global__ __launch_bounds__(256, 2) void cbow_gemm_kernel(
    const unsigned short* __restrict__ A,    // [BATCH][128] bf16 (summed)
    const unsigned short* __restrict__ Wb,   // [VOCAB][128] bf16
    const float* __restrict__ bias,          // [VOCAB]
    float* __restrict__ C)                   // [BATCH][VOCAB]
{
    const int tid  = threadIdx.x;
    const int wave = tid >> 6;
    const int lane = tid & 63;
    const int lr   = lane & 15;   // free-dim index inside 16x16 tile
    const int quad = lane >> 4;   // k-chunk / output-col selector
    const int nwave = blockIdx.x * 256 + wave * 64;  // vocab start, this wave

    // W fragments: loaded ONCE, live for the whole block. 64 VGPRs.
    // A-operand: W[n][k]; m_mfma = lr -> vocab row, k = s*32 + quad*8 + j.
    bf16x8 wf[4][4];
#pragma unroll
    for (int nt = 0; nt < 4; ++nt) {
        const unsigned short* wrow =
            Wb + (size_t)(nwave + nt * 16 + lr) * EMBED;
#pragma unroll
        for (int s = 0; s < 4; ++s)
            wf[nt][s] = *(const bf16x8*)(wrow + s * 32 + quad * 8);
    }

    // Bias, loaded once. Output col n = nwave + nt*16 + quad*4 + reg.
    f32x4 bv[4];
#pragma unroll
    for (int nt = 0; nt < 4; ++nt)
        bv[nt] = *(const f32x4*)(bias + nwave + nt * 16 + quad * 4);

    // Loop over this block's 8 m-tiles (512 batch rows per block).
    for (int mb = 0; mb < 8; ++mb) {
        const int mbase = (blockIdx.y * 8 + mb) * 64;

        // B-operand frags: summed[m][k]; n_mfma = lr -> batch row.
        // A is 1 MB and L2-hot (nontemporal C stores keep it resident).
        bf16x8 bfrag[4][4];
#pragma unroll
        for (int mt = 0; mt < 4; ++mt) {
            const unsigned short* row =
                A + (size_t)(mbase + mt * 16 + lr) * EMBED;
#pragma unroll
            for (int s = 0; s < 4; ++s)
                bfrag[mt][s] = *(const bf16x8*)(row + s * 32 + quad * 8);
        }

        f32x4 acc[4][4];
#pragma unroll
        for (int nt = 0; nt < 4; ++nt)
#pragma unroll
            for (int mt = 0; mt < 4; ++mt)
                acc[nt][mt] = (f32x4){0.f, 0.f, 0.f, 0.f};

#pragma unroll
        for (int nt = 0; nt < 4; ++nt)
#pragma unroll
            for (int s = 0; s < 4; ++s)
#pragma unroll
                for (int mt = 0; mt < 4; ++mt)
                    acc[nt][mt] = __builtin_amdgcn_mfma_f32_16x16x32_bf16(
                        wf[nt][s], bfrag[mt][s], acc[nt][mt], 0, 0, 0);

        // Epilogue: vocab n = nwave + nt*16 + quad*4 + reg, batch m = lr-row.
#pragma unroll
        for (int nt = 0; nt < 4; ++nt) {
            const int n0 = nwave + nt * 16 + quad * 4;
#pragma unroll
            for (int mt = 0; mt < 4; ++mt) {
                const int m = mbase + mt * 16 + lr;
                const f32x4 v = acc[nt][mt] + bv[nt];
                __builtin_nontemporal_store(
                    v, (f32x4*)(C + (size_t)m * VOCAB + n0));
            }
        }
    }
}

extern "C" void kernel_launch(void* const* d_in, const int* in_sizes, int n_in,
                              void* d_out, int out_size, void* d_ws, size_t ws_size,
                              hipStream_t stream) {
    const int*   x    = (const int*)d_in[0];     // [4096,8]
    const float* emb  = (const float*)d_in[1];   // [32000,128]
    const float* W    = (const float*)d_in[2];   // [32000,128]
    const float* bias = (const float*)d_in[3];   // [32000]
    float* out = (float*)d_out;                  // [4096,32000]

    unsigned short* A  = (unsigned short*)d_ws;            // 1 MB: summed bf16
    unsigned short* Wb = A + (size_t)BATCH * EMBED;        // 8.2 MB: W bf16

    gather_sum_kernel<<<BATCH, EMBED, 0, stream>>>(x, emb, A);
    convert_w_kernel<<<(VOCAB * EMBED / 4) / 256, 256, 0, stream>>>(W, Wb);

    dim3 grid(VOCAB / 256, BATCH / (8 * 64));   // 125 x 8 = 1000 blocks
    cbow_gemm_kernel<<<grid, 256, 0, stream>>>(A, Wb, bias, out);
}